// Round 1
// baseline (1358.599 us; speedup 1.0000x reference)
//
#include <hip/hip_runtime.h>
#include <hip/hip_bf16.h>

#define NND 100000
#define NED 1200000
#define NHOP 3
#define DM 64
#define EPSV 1e-5f

typedef long long i64;

__device__ __forceinline__ float rlf(float v, int k) {
    return __builtin_bit_cast(float, __builtin_amdgcn_readlane(__builtin_bit_cast(int, v), k));
}

// --- softmax of comb_w rows: [4][3] -> wsoft ---
__global__ void k_weights(const float* __restrict__ comb_w, float* __restrict__ wsoft) {
    int j = threadIdx.x;
    if (j < NHOP + 1) {
        float a0 = comb_w[j * 3 + 0], a1 = comb_w[j * 3 + 1], a2 = comb_w[j * 3 + 2];
        float mx = fmaxf(a0, fmaxf(a1, a2));
        float e0 = expf(a0 - mx), e1 = expf(a1 - mx), e2 = expf(a2 - mx);
        float s = 1.0f / (e0 + e1 + e2);
        wsoft[j * 3 + 0] = e0 * s; wsoft[j * 3 + 1] = e1 * s; wsoft[j * 3 + 2] = e2 * s;
    }
}

// --- xw = (sum_i w[j,i]*bb[1+i]) @ W   (bias dropped: BN cancels it exactly) ---
__global__ __launch_bounds__(256) void k_gemm(const float* __restrict__ bb,
                                              const float* __restrict__ wsoft, int j,
                                              const float* __restrict__ W,
                                              float* __restrict__ xw) {
    const int lane = threadIdx.x & 63;
    float Wcol[DM];
#pragma unroll
    for (int k = 0; k < DM; k++) Wcol[k] = W[k * DM + lane];
    const float w0 = wsoft[j * 3 + 0], w1 = wsoft[j * 3 + 1], w2 = wsoft[j * 3 + 2];
    const float* b1 = bb + (i64)1 * NND * DM;
    const float* b2 = bb + (i64)2 * NND * DM;
    const float* b3 = bb + (i64)3 * NND * DM;
    int wave = (int)((blockIdx.x * blockDim.x + threadIdx.x) >> 6);
    int nw = (int)((gridDim.x * blockDim.x) >> 6);
    for (int n = wave; n < NND; n += nw) {
        i64 base = (i64)n * DM + lane;
        float m = w0 * b1[base] + w1 * b2[base] + w2 * b3[base];
        float a0 = 0.f, a1 = 0.f, a2 = 0.f, a3 = 0.f;
#pragma unroll
        for (int k = 0; k < DM; k += 4) {
            a0 = fmaf(rlf(m, k + 0), Wcol[k + 0], a0);
            a1 = fmaf(rlf(m, k + 1), Wcol[k + 1], a1);
            a2 = fmaf(rlf(m, k + 2), Wcol[k + 2], a2);
            a3 = fmaf(rlf(m, k + 3), Wcol[k + 3], a3);
        }
        xw[base] = (a0 + a1) + (a2 + a3);
    }
}

// --- degree count (without +1): deg[n] = #in-edges ---
__global__ __launch_bounds__(256) void k_deg(const int* __restrict__ dst, float* __restrict__ deg) {
    int i = blockIdx.x * blockDim.x + threadIdx.x;
    int stride = gridDim.x * blockDim.x;
    for (int e = i; e < NED; e += stride) unsafeAtomicAdd(&deg[dst[e]], 1.0f);
}

// --- edge scatter: agg[dst] += xw[src] * rsqrt((deg_s+1)(deg_d+1)) ---
// NED divisible by 64: each wave loads 64 edges coalesced, then readlane-broadcasts.
__global__ __launch_bounds__(256) void k_scatter(const int* __restrict__ src,
                                                 const int* __restrict__ dst,
                                                 const float* __restrict__ deg,
                                                 const float* __restrict__ xw,
                                                 float* __restrict__ agg) {
    const int lane = threadIdx.x & 63;
    int wave = (int)((blockIdx.x * blockDim.x + threadIdx.x) >> 6);
    int nw = (int)((gridDim.x * blockDim.x) >> 6);
    for (int ebase = wave * 64; ebase < NED; ebase += nw * 64) {
        int s = src[ebase + lane];
        int d = dst[ebase + lane];
        float cf = rsqrtf((deg[s] + 1.0f) * (deg[d] + 1.0f));
        for (int t = 0; t < 64; t++) {
            int ss = __builtin_amdgcn_readlane(s, t);
            int dd = __builtin_amdgcn_readlane(d, t);
            float c = rlf(cf, t);
            float v = xw[(i64)ss * DM + lane] * c;
            unsafeAtomicAdd(&agg[(i64)dd * DM + lane], v);
        }
    }
}

// --- per-feature sum / sumsq of prop (self-loop fused on the fly) ---
// conv=0: x = xw ; conv=1: x = agg + xw/(deg+1)
__global__ __launch_bounds__(256) void k_stats(const float* __restrict__ xw,
                                               const float* __restrict__ agg,
                                               const float* __restrict__ deg, int conv,
                                               float* __restrict__ stats) {
    const int lane = threadIdx.x & 63;
    const int row = threadIdx.x >> 6;
    int gw = blockIdx.x * 4 + row;
    int nw = gridDim.x * 4;
    float s = 0.f, sq = 0.f;
    for (int n = gw; n < NND; n += nw) {
        i64 i = (i64)n * DM + lane;
        float x;
        if (conv) x = agg[i] + xw[i] / (deg[n] + 1.0f);
        else      x = xw[i];
        s += x; sq += x * x;
    }
    __shared__ float ls[4][DM], lq[4][DM];
    ls[row][lane] = s; lq[row][lane] = sq;
    __syncthreads();
    if (row == 0) {
        s  = ls[0][lane] + ls[1][lane] + ls[2][lane] + ls[3][lane];
        sq = lq[0][lane] + lq[1][lane] + lq[2][lane] + lq[3][lane];
        unsafeAtomicAdd(&stats[lane], s);
        unsafeAtomicAdd(&stats[DM + lane], sq);
    }
}

// --- BN apply + accumulate into hidden; mode 2 also does log_softmax and writes out ---
// mode 0: hidden  = BN(xw)                     (ego)
// mode 1: hidden += relu(BN(agg + selfloop))   (conv hops 0,1)
// mode 2: h = hidden + relu(BN(...)); out = log_softmax(h) over the 64 lanes
__global__ __launch_bounds__(256) void k_apply(const float* __restrict__ xw,
                                               const float* __restrict__ agg,
                                               const float* __restrict__ deg, int mode,
                                               const float* __restrict__ stats,
                                               float* __restrict__ hidden,
                                               float* __restrict__ out) {
    const int lane = threadIdx.x & 63;
    float mean = stats[lane] * (1.0f / NND);
    float var = stats[DM + lane] * (1.0f / NND) - mean * mean;
    float inv = rsqrtf(var + EPSV);
    int wave = (int)((blockIdx.x * blockDim.x + threadIdx.x) >> 6);
    int nw = (int)((gridDim.x * blockDim.x) >> 6);
    for (int n = wave; n < NND; n += nw) {
        i64 i = (i64)n * DM + lane;
        float x;
        if (mode != 0) x = agg[i] + xw[i] / (deg[n] + 1.0f);
        else           x = xw[i];
        float bn = (x - mean) * inv;
        if (mode == 0) {
            hidden[i] = bn;
        } else if (mode == 1) {
            hidden[i] += fmaxf(bn, 0.0f);
        } else {
            float h = hidden[i] + fmaxf(bn, 0.0f);
            float mx = h;
#pragma unroll
            for (int off = 32; off >= 1; off >>= 1) mx = fmaxf(mx, __shfl_xor(mx, off));
            float e = expf(h - mx);
            float ssum = e;
#pragma unroll
            for (int off = 32; off >= 1; off >>= 1) ssum += __shfl_xor(ssum, off);
            out[i] = h - mx - logf(ssum);
        }
    }
}

extern "C" void kernel_launch(void* const* d_in, const int* in_sizes, int n_in,
                              void* d_out, int out_size, void* d_ws, size_t ws_size,
                              hipStream_t stream) {
    const float* bb     = (const float*)d_in[0];
    const float* comb_w = (const float*)d_in[1];
    const float* ego_W  = (const float*)d_in[2];
    const float* conv_W = (const float*)d_in[4];
    const int*   edges  = (const int*)d_in[6];
    float* out = (float*)d_out;

    const i64 NF = (i64)NND * DM;
    char* ws = (char*)d_ws;
    float* wsoft = (float*)ws;                       // 12 floats
    float* xw    = (float*)(ws + 256);               // NF floats
    float* agg   = xw + NF;                          // NF floats
    float* deg   = agg + NF;                         // NND floats
    float* stats = deg + NND;                        // 128 floats
    float* hidden = out;                             // alias d_out as hidden accumulator

    k_weights<<<1, 64, 0, stream>>>(comb_w, wsoft);

    // ego path: xw0 = multi0 @ ego_W ; hidden = BN(xw0)
    k_gemm<<<1024, 256, 0, stream>>>(bb, wsoft, 0, ego_W, xw);
    hipMemsetAsync(stats, 0, 2 * DM * sizeof(float), stream);
    k_stats<<<512, 256, 0, stream>>>(xw, xw, deg, 0, stats);
    k_apply<<<512, 256, 0, stream>>>(xw, xw, deg, 0, stats, hidden, out);

    for (int k = 0; k < NHOP; k++) {
        const int* src = edges + (i64)k * 2 * NED;
        const int* dst = src + NED;
        k_gemm<<<1024, 256, 0, stream>>>(bb, wsoft, k + 1, conv_W + (i64)k * DM * DM, xw);
        hipMemsetAsync(deg, 0, NND * sizeof(float), stream);
        k_deg<<<1024, 256, 0, stream>>>(dst, deg);
        hipMemsetAsync(agg, 0, NF * sizeof(float), stream);
        k_scatter<<<2048, 256, 0, stream>>>(src, dst, deg, xw, agg);
        hipMemsetAsync(stats, 0, 2 * DM * sizeof(float), stream);
        k_stats<<<512, 256, 0, stream>>>(xw, agg, deg, 1, stats);
        int mode = (k == NHOP - 1) ? 2 : 1;
        k_apply<<<512, 256, 0, stream>>>(xw, agg, deg, mode, stats, hidden, out);
    }
}

// Round 2
// 1015.533 us; speedup vs baseline: 1.3378x; 1.3378x over previous
//
#include <hip/hip_runtime.h>
#include <hip/hip_bf16.h>

#define NND 100000
#define NED 1200000
#define NHOP 3
#define DM 64
#define EPSV 1e-5f
#define NB1 391   // ceil(NND/256)

typedef long long i64;

__device__ __forceinline__ float rlf(float v, int k) {
    return __builtin_bit_cast(float, __builtin_amdgcn_readlane(__builtin_bit_cast(int, v), k));
}

// --- softmax of comb_w rows: [4][3] -> wsoft ---
__global__ void k_weights(const float* __restrict__ comb_w, float* __restrict__ wsoft) {
    int j = threadIdx.x;
    if (j < NHOP + 1) {
        float a0 = comb_w[j * 3 + 0], a1 = comb_w[j * 3 + 1], a2 = comb_w[j * 3 + 2];
        float mx = fmaxf(a0, fmaxf(a1, a2));
        float e0 = expf(a0 - mx), e1 = expf(a1 - mx), e2 = expf(a2 - mx);
        float s = 1.0f / (e0 + e1 + e2);
        wsoft[j * 3 + 0] = e0 * s; wsoft[j * 3 + 1] = e1 * s; wsoft[j * 3 + 2] = e2 * s;
    }
}

// --- xw = (sum_i w[j,i]*bb[1+i]) @ W ; optional row-scale by dinv[n]; optional BN-stats ---
__global__ __launch_bounds__(256) void k_gemm(const float* __restrict__ bb,
                                              const float* __restrict__ wsoft, int j,
                                              const float* __restrict__ W,
                                              const float* __restrict__ dinv, int scale,
                                              float* __restrict__ stats, int dostats,
                                              float* __restrict__ xw) {
    const int lane = threadIdx.x & 63;
    float Wcol[DM];
#pragma unroll
    for (int k = 0; k < DM; k++) Wcol[k] = W[k * DM + lane];
    const float w0 = wsoft[j * 3 + 0], w1 = wsoft[j * 3 + 1], w2 = wsoft[j * 3 + 2];
    const float* b1 = bb + (i64)1 * NND * DM;
    const float* b2 = bb + (i64)2 * NND * DM;
    const float* b3 = bb + (i64)3 * NND * DM;
    int wave = (int)((blockIdx.x * blockDim.x + threadIdx.x) >> 6);
    int nw = (int)((gridDim.x * blockDim.x) >> 6);
    float s = 0.f, sq = 0.f;
    for (int n = wave; n < NND; n += nw) {
        i64 base = (i64)n * DM + lane;
        float m = w0 * b1[base] + w1 * b2[base] + w2 * b3[base];
        float a0 = 0.f, a1 = 0.f, a2 = 0.f, a3 = 0.f;
#pragma unroll
        for (int k = 0; k < DM; k += 4) {
            a0 = fmaf(rlf(m, k + 0), Wcol[k + 0], a0);
            a1 = fmaf(rlf(m, k + 1), Wcol[k + 1], a1);
            a2 = fmaf(rlf(m, k + 2), Wcol[k + 2], a2);
            a3 = fmaf(rlf(m, k + 3), Wcol[k + 3], a3);
        }
        float r = (a0 + a1) + (a2 + a3);
        if (scale) r *= dinv[n];
        xw[base] = r;
        s += r; sq += r * r;
    }
    if (dostats) {
        __shared__ float ls[4][DM], lq[4][DM];
        int row = threadIdx.x >> 6;
        ls[row][lane] = s; lq[row][lane] = sq;
        __syncthreads();
        if (row == 0) {
            s  = ls[0][lane] + ls[1][lane] + ls[2][lane] + ls[3][lane];
            sq = lq[0][lane] + lq[1][lane] + lq[2][lane] + lq[3][lane];
            unsafeAtomicAdd(&stats[lane], s);
            unsafeAtomicAdd(&stats[DM + lane], sq);
        }
    }
}

// --- integer in-degree histogram ---
__global__ __launch_bounds__(256) void k_deg(const int* __restrict__ dst, int* __restrict__ deg) {
    int i = blockIdx.x * blockDim.x + threadIdx.x;
    int stride = gridDim.x * blockDim.x;
    for (int e = i; e < NED; e += stride) atomicAdd(&deg[dst[e]], 1);
}

// --- scan level 1: per-block exclusive scan of deg; block totals; dinv ---
__global__ __launch_bounds__(256) void k_scan1(const int* __restrict__ deg,
                                               int* __restrict__ off,
                                               int* __restrict__ partials,
                                               float* __restrict__ dinv) {
    int t = threadIdx.x;
    int n = blockIdx.x * 256 + t;
    int d = (n < NND) ? deg[n] : 0;
    if (n < NND) dinv[n] = rsqrtf((float)d + 1.0f);
    __shared__ int sh[256];
    sh[t] = d;
    __syncthreads();
    for (int o = 1; o < 256; o <<= 1) {
        int v = (t >= o) ? sh[t - o] : 0;
        __syncthreads();
        sh[t] += v;
        __syncthreads();
    }
    if (n < NND) off[n] = sh[t] - d;       // local exclusive
    if (t == 255) partials[blockIdx.x] = sh[255];
}

// --- scan level 2: exclusive scan of 391 block totals ---
__global__ __launch_bounds__(512) void k_scan2(int* __restrict__ partials) {
    int t = threadIdx.x;
    int d = (t < NB1) ? partials[t] : 0;
    __shared__ int sh[512];
    sh[t] = d;
    __syncthreads();
    for (int o = 1; o < 512; o <<= 1) {
        int v = (t >= o) ? sh[t - o] : 0;
        __syncthreads();
        sh[t] += v;
        __syncthreads();
    }
    if (t < NB1) partials[t] = sh[t] - d;  // exclusive block base
}

// --- scan level 3: add block bases ---
__global__ __launch_bounds__(256) void k_scan3(int* __restrict__ off,
                                               const int* __restrict__ partials) {
    int n = blockIdx.x * 256 + threadIdx.x;
    if (n < NND) off[n] += partials[blockIdx.x];
}

// --- bucket: sortedsrc grouped by dst ---
__global__ __launch_bounds__(256) void k_bucket(const int* __restrict__ src,
                                                const int* __restrict__ dst,
                                                const int* __restrict__ off,
                                                int* __restrict__ cursor,
                                                int* __restrict__ sortedsrc) {
    int i = blockIdx.x * blockDim.x + threadIdx.x;
    int stride = gridDim.x * blockDim.x;
    for (int e = i; e < NED; e += stride) {
        int d = dst[e];
        int pos = off[d] + atomicAdd(&cursor[d], 1);
        sortedsrc[pos] = src[e];
    }
}

// --- gather aggregation: x[n] = (sum_{src in N(n)} xws[src] + xws[n]) * dinv[n]; fused stats ---
__global__ __launch_bounds__(256) void k_gather(const float* __restrict__ xws,
                                                const int* __restrict__ sortedsrc,
                                                const int* __restrict__ off,
                                                const int* __restrict__ deg,
                                                const float* __restrict__ dinv,
                                                float* __restrict__ xbuf,
                                                float* __restrict__ stats) {
    const int lane = threadIdx.x & 63;
    int wave = (int)((blockIdx.x * blockDim.x + threadIdx.x) >> 6);
    int nw = (int)((gridDim.x * blockDim.x) >> 6);
    float s = 0.f, sq = 0.f;
    for (int n = wave; n < NND; n += nw) {
        float acc = xws[(i64)n * DM + lane];   // self-loop term (pre-scaled)
        int start = off[n];
        int cnt = deg[n];
        int i = 0;
        while (i < cnt) {
            int m = cnt - i; if (m > 64) m = 64;
            int sl = (lane < m) ? sortedsrc[start + i + lane] : 0;
            for (int t = 0; t < m; t++) {
                int ss = __builtin_amdgcn_readlane(sl, t);
                acc += xws[(i64)ss * DM + lane];
            }
            i += m;
        }
        float x = acc * dinv[n];
        xbuf[(i64)n * DM + lane] = x;
        s += x; sq += x * x;
    }
    __shared__ float ls[4][DM], lq[4][DM];
    int row = threadIdx.x >> 6;
    ls[row][lane] = s; lq[row][lane] = sq;
    __syncthreads();
    if (row == 0) {
        s  = ls[0][lane] + ls[1][lane] + ls[2][lane] + ls[3][lane];
        sq = lq[0][lane] + lq[1][lane] + lq[2][lane] + lq[3][lane];
        unsafeAtomicAdd(&stats[lane], s);
        unsafeAtomicAdd(&stats[DM + lane], sq);
    }
}

// --- BN apply + accumulate into hidden; mode 2 adds log_softmax + writes out ---
__global__ __launch_bounds__(256) void k_apply(const float* __restrict__ xbuf, int mode,
                                               const float* __restrict__ stats,
                                               float* __restrict__ hidden,
                                               float* __restrict__ out) {
    const int lane = threadIdx.x & 63;
    float mean = stats[lane] * (1.0f / NND);
    float var = stats[DM + lane] * (1.0f / NND) - mean * mean;
    float inv = rsqrtf(var + EPSV);
    int wave = (int)((blockIdx.x * blockDim.x + threadIdx.x) >> 6);
    int nw = (int)((gridDim.x * blockDim.x) >> 6);
    for (int n = wave; n < NND; n += nw) {
        i64 i = (i64)n * DM + lane;
        float bn = (xbuf[i] - mean) * inv;
        if (mode == 0) {
            hidden[i] = bn;
        } else if (mode == 1) {
            hidden[i] += fmaxf(bn, 0.0f);
        } else {
            float h = hidden[i] + fmaxf(bn, 0.0f);
            float mx = h;
#pragma unroll
            for (int off = 32; off >= 1; off >>= 1) mx = fmaxf(mx, __shfl_xor(mx, off));
            float e = expf(h - mx);
            float ssum = e;
#pragma unroll
            for (int off = 32; off >= 1; off >>= 1) ssum += __shfl_xor(ssum, off);
            out[i] = h - mx - logf(ssum);
        }
    }
}

extern "C" void kernel_launch(void* const* d_in, const int* in_sizes, int n_in,
                              void* d_out, int out_size, void* d_ws, size_t ws_size,
                              hipStream_t stream) {
    const float* bb     = (const float*)d_in[0];
    const float* comb_w = (const float*)d_in[1];
    const float* ego_W  = (const float*)d_in[2];
    const float* conv_W = (const float*)d_in[4];
    const int*   edges  = (const int*)d_in[6];
    float* out = (float*)d_out;

    const i64 NF = (i64)NND * DM;
    char* ws = (char*)d_ws;
    float* wsoft     = (float*)ws;                  // 64 f
    float* stats     = wsoft + 64;                  // 128 f
    float* xws       = stats + 128;                 // NF f
    float* xbuf      = xws + NF;                    // NF f
    float* dinv      = xbuf + NF;                   // NND f
    int*   deg       = (int*)(dinv + NND);          // NND i
    int*   off       = deg + NND;                   // NND i
    int*   cursor    = off + NND;                   // NND i
    int*   partials  = cursor + NND;                // 512 i
    int*   sortedsrc = partials + 512;              // NED i
    float* hidden = out;                            // alias d_out as accumulator

    k_weights<<<1, 64, 0, stream>>>(comb_w, wsoft);

    // ego path: xws = multi0 @ ego_W (unscaled, stats fused); hidden = BN(xws)
    hipMemsetAsync(stats, 0, 2 * DM * sizeof(float), stream);
    k_gemm<<<1024, 256, 0, stream>>>(bb, wsoft, 0, ego_W, dinv, 0, stats, 1, xws);
    k_apply<<<512, 256, 0, stream>>>(xws, 0, stats, hidden, out);

    for (int k = 0; k < NHOP; k++) {
        const int* src = edges + (i64)k * 2 * NED;
        const int* dst = src + NED;
        // CSR build
        hipMemsetAsync(deg, 0, NND * sizeof(int), stream);
        hipMemsetAsync(cursor, 0, NND * sizeof(int), stream);
        hipMemsetAsync(stats, 0, 2 * DM * sizeof(float), stream);
        k_deg<<<1024, 256, 0, stream>>>(dst, deg);
        k_scan1<<<NB1, 256, 0, stream>>>(deg, off, partials, dinv);
        k_scan2<<<1, 512, 0, stream>>>(partials);
        k_scan3<<<NB1, 256, 0, stream>>>(off, partials);
        k_bucket<<<1024, 256, 0, stream>>>(src, dst, off, cursor, sortedsrc);
        // xws = (blend @ W_k) * dinv[n]
        k_gemm<<<1024, 256, 0, stream>>>(bb, wsoft, k + 1, conv_W + (i64)k * DM * DM,
                                         dinv, 1, stats, 0, xws);
        // gather + self-loop + stats
        k_gather<<<2048, 256, 0, stream>>>(xws, sortedsrc, off, deg, dinv, xbuf, stats);
        int mode = (k == NHOP - 1) ? 2 : 1;
        k_apply<<<512, 256, 0, stream>>>(xbuf, mode, stats, hidden, out);
    }
}